// Round 1
// baseline (552.904 us; speedup 1.0000x reference)
//
#include <hip/hip_runtime.h>

#define MWIN 2048
#define HH 8
#define DD 16

// ---------------- Kernel 1: qkv[n, j] = sum_k x[n,k] * Wqkv[j,k] ----------------
// 64x64 output tile per block, 256 threads, 4x4 micro-tile per thread.
__global__ __launch_bounds__(256) void k_qkv_gemm(const float* __restrict__ x,
                                                  const float* __restrict__ W,
                                                  float* __restrict__ qkv, int N) {
    __shared__ float xs[64][129];   // +1 pad: inner-loop reads are <=2-way (free)
    __shared__ float wsh[64][129];
    int tid = threadIdx.x;
    int row0 = blockIdx.x * 64;
    int col0 = blockIdx.y * 64;     // 0..320, always valid (384 rows in W)
    for (int i = 0; i < 8; ++i) {
        int li = i * 256 + tid;     // float4 id 0..2047
        int r  = li >> 5;           // 32 float4 per 128-wide row
        int c4 = li & 31;
        int gr = row0 + r;
        float4 v = make_float4(0.f, 0.f, 0.f, 0.f);
        if (gr < N) v = ((const float4*)(x + (size_t)gr * 128))[c4];
        xs[r][c4 * 4 + 0] = v.x; xs[r][c4 * 4 + 1] = v.y;
        xs[r][c4 * 4 + 2] = v.z; xs[r][c4 * 4 + 3] = v.w;
        float4 wv = ((const float4*)(W + (size_t)(col0 + r) * 128))[c4];
        wsh[r][c4 * 4 + 0] = wv.x; wsh[r][c4 * 4 + 1] = wv.y;
        wsh[r][c4 * 4 + 2] = wv.z; wsh[r][c4 * 4 + 3] = wv.w;
    }
    __syncthreads();
    int tx = tid & 15, ty = tid >> 4;
    float acc[4][4] = {};
    #pragma unroll 4
    for (int k = 0; k < 128; ++k) {
        float a[4], b[4];
        #pragma unroll
        for (int i = 0; i < 4; ++i) a[i] = xs[ty * 4 + i][k];
        #pragma unroll
        for (int j = 0; j < 4; ++j) b[j] = wsh[tx * 4 + j][k];
        #pragma unroll
        for (int i = 0; i < 4; ++i)
            #pragma unroll
            for (int j = 0; j < 4; ++j) acc[i][j] += a[i] * b[j];
    }
    #pragma unroll
    for (int i = 0; i < 4; ++i) {
        int gr = row0 + ty * 4 + i;
        if (gr >= N) continue;
        float4 o = make_float4(acc[i][0], acc[i][1], acc[i][2], acc[i][3]);
        *(float4*)(qkv + (size_t)gr * 384 + col0 + tx * 4) = o;
    }
}

// ---------------- Kernel 2: per-(window,head) kv & s reduction ----------------
// kv[w,h,d,e] = sum_p relu(k[p,h,d]) * v[p,h,e];  s[w,h,d] = sum_p relu(k[p,h,d])
__global__ __launch_bounds__(256) void k_kv_accum(const float* __restrict__ qkv,
                                                  const int* __restrict__ offsets,
                                                  const int* __restrict__ counts,
                                                  float* __restrict__ kv,
                                                  float* __restrict__ s) {
    int w = blockIdx.x, h = blockIdx.y;
    int tid = threadIdx.x;
    int d = tid >> 4, e = tid & 15;
    __shared__ float kb[16][16];
    __shared__ float vb[16][17];
    int off = offsets[w], cnt = counts[w];
    float acc = 0.f, sacc = 0.f;
    for (int base = 0; base < cnt; base += 16) {
        int pl = tid >> 4, c = tid & 15;
        int p = base + pl;
        float kval = 0.f, vval = 0.f;
        if (p < cnt) {
            const float* row = qkv + (size_t)(off + p) * 384 + h * 16;
            kval = row[128 + c];
            vval = row[256 + c];
        }
        kb[pl][c] = kval > 0.f ? kval : 0.f;
        vb[pl][c] = vval;
        __syncthreads();
        int lim = min(16, cnt - base);
        for (int p2 = 0; p2 < lim; ++p2) {
            float kk = kb[p2][d];
            acc += kk * vb[p2][e];
            if (e == 0) sacc += kk;
        }
        __syncthreads();
    }
    kv[((size_t)(w * HH + h) * 16 + d) * 16 + e] = acc;
    if (e == 0) s[(size_t)(w * HH + h) * 16 + d] = sacc;
}

// ---------------- Kernel 3: 3x3 grid pooling (windows on a 2x32x32 grid) ------
__global__ __launch_bounds__(256) void k_pool(const float* __restrict__ in,
                                              float* __restrict__ out,
                                              int shift, int total) {
    int idx = blockIdx.x * 256 + threadIdx.x;
    if (idx >= total) return;
    int w = idx >> shift;
    int rest = idx & ((1 << shift) - 1);
    int b = w >> 10, y = (w >> 5) & 31, xx = w & 31;
    float acc = 0.f;
    #pragma unroll
    for (int dy = -1; dy <= 1; ++dy)
        #pragma unroll
        for (int dx = -1; dx <= 1; ++dx) {
            int ny = y + dy, nx = xx + dx;
            if (ny < 0 || ny >= 32 || nx < 0 || nx >= 32) continue;
            int nw = (b << 10) | (ny << 5) | nx;
            acc += in[((size_t)nw << shift) + rest];
        }
    out[idx] = acc;
}

// ---------------- Kernel 4: fused attention + output projection ----------------
// 16 points per block. Phase 1: y[h,e] = q.kvp / (q.sp + 1e-6) into LDS.
// Phase 2: out = y @ Wproj^T + bproj with Wproj staged transposed in LDS.
__global__ __launch_bounds__(256) void k_attn_proj(const float* __restrict__ qkv,
                                                   const float* __restrict__ kvp,
                                                   const float* __restrict__ sp,
                                                   const int* __restrict__ winds,
                                                   const float* __restrict__ Wp,
                                                   const float* __restrict__ bp,
                                                   float* __restrict__ out, int N) {
    __shared__ float ys[16][128];
    __shared__ float wp[128][132];   // transposed: wp[k][c] = Wp[c*128+k]; pad keeps 2-way
    int tid = threadIdx.x;
    for (int i = 0; i < 16; ++i) {
        int li = i * 256 + tid;      // float4 id 0..4095
        int c = li >> 5;
        int k4 = li & 31;
        float4 v = ((const float4*)Wp)[li];
        wp[k4 * 4 + 0][c] = v.x; wp[k4 * 4 + 1][c] = v.y;
        wp[k4 * 4 + 2][c] = v.z; wp[k4 * 4 + 3][c] = v.w;
    }
    int n0 = blockIdx.x * 16;
    for (int rep = 0; rep < 8; ++rep) {
        int li = rep * 256 + tid;    // 0..2047
        int pl = li >> 7;
        int j  = li & 127;
        int n = n0 + pl;
        float yv = 0.f;
        if (n < N) {
            int w = winds[n];
            int h = j >> 4, e = j & 15;
            const float* qrow = qkv + (size_t)n * 384 + h * 16;
            const float* kvw  = kvp + (size_t)(w * HH + h) * 256 + e;
            const float* sw   = sp  + (size_t)(w * HH + h) * 16;
            float y = 0.f, z = 0.f;
            #pragma unroll
            for (int dd = 0; dd < 16; ++dd) {
                float qv = qrow[dd];
                qv = qv > 0.f ? qv : 0.f;
                y += qv * kvw[dd * 16];
                z += qv * sw[dd];
            }
            yv = y / (z + 1e-6f);
        }
        ys[pl][j] = yv;
    }
    __syncthreads();
    for (int rep = 0; rep < 8; ++rep) {
        int li = rep * 256 + tid;
        int pl = li >> 7;
        int c  = li & 127;
        int n = n0 + pl;
        if (n >= N) continue;
        float acc = bp[c];
        const float4* yrow = (const float4*)&ys[pl][0];
        #pragma unroll 8
        for (int k4 = 0; k4 < 32; ++k4) {
            float4 yv = yrow[k4];
            acc += yv.x * wp[4 * k4 + 0][c] + yv.y * wp[4 * k4 + 1][c] +
                   yv.z * wp[4 * k4 + 2][c] + yv.w * wp[4 * k4 + 3][c];
        }
        out[(size_t)n * 128 + c] = acc;
    }
}

extern "C" void kernel_launch(void* const* d_in, const int* in_sizes, int n_in,
                              void* d_out, int out_size, void* d_ws, size_t ws_size,
                              hipStream_t stream) {
    const float* x     = (const float*)d_in[0];
    const float* Wqkv  = (const float*)d_in[1];
    const float* Wproj = (const float*)d_in[2];
    const float* bproj = (const float*)d_in[3];
    const int*   offsets = (const int*)d_in[4];
    const int*   counts  = (const int*)d_in[5];
    const int*   winds   = (const int*)d_in[6];
    // d_in[7] = batch_win_coords (unused; derived from window id)

    int N = in_sizes[0] / 128;
    float* ws   = (float*)d_ws;
    float* qkv  = ws;                                   // N*384
    float* kv   = qkv + (size_t)N * 384;                // M*H*256
    float* s    = kv  + (size_t)MWIN * HH * 256;        // M*H*16
    float* kvp  = s   + (size_t)MWIN * HH * 16;         // M*H*256
    float* sp   = kvp + (size_t)MWIN * HH * 256;        // M*H*16
    float* out  = (float*)d_out;

    dim3 g1((N + 63) / 64, 6);
    k_qkv_gemm<<<g1, 256, 0, stream>>>(x, Wqkv, qkv, N);

    dim3 g2(MWIN, HH);
    k_kv_accum<<<g2, 256, 0, stream>>>(qkv, offsets, counts, kv, s);

    int tot_kv = MWIN * HH * 256;   // shift 11 (2048 per window)
    k_pool<<<(tot_kv + 255) / 256, 256, 0, stream>>>(kv, kvp, 11, tot_kv);
    int tot_s = MWIN * HH * 16;     // shift 7 (128 per window)
    k_pool<<<(tot_s + 255) / 256, 256, 0, stream>>>(s, sp, 7, tot_s);

    k_attn_proj<<<(N + 15) / 16, 256, 0, stream>>>(qkv, kvp, sp, winds, Wproj, bproj, out, N);
}

// Round 2
// 488.777 us; speedup vs baseline: 1.1312x; 1.1312x over previous
//
#include <hip/hip_runtime.h>

#define MWIN 2048
#define HH 8
#define DD 16

// ---------------- Generic 64x64-tile GEMM: out[n, col0+c] = A[n,:128] . Bw[col0+c, :128] (+bias) ----
// K is fixed at 128. LDS tiles stored TRANSPOSED [k][row] so the inner loop is
// 2x ds_read_b128 + 16 v_fma per k. Pad row to 68 floats (16B-aligned float4 reads).
__global__ __launch_bounds__(256) void k_gemm128(const float* __restrict__ A, int lda,
                                                 const float* __restrict__ Bw,
                                                 const float* __restrict__ bias,
                                                 float* __restrict__ out, int ldo, int N) {
    __shared__ float ast[128][68];
    __shared__ float bst[128][68];
    int tid = threadIdx.x;
    int row0 = blockIdx.x * 64;
    int col0 = blockIdx.y * 64;
    for (int i = 0; i < 8; ++i) {
        int li = i * 256 + tid;     // float4 id 0..2047
        int r  = li >> 5;           // tile row 0..63
        int c4 = li & 31;           // float4 along k
        int gr = row0 + r;
        float4 v = make_float4(0.f, 0.f, 0.f, 0.f);
        if (gr < N) v = *(const float4*)(A + (size_t)gr * lda + c4 * 4);
        ast[c4 * 4 + 0][r] = v.x; ast[c4 * 4 + 1][r] = v.y;
        ast[c4 * 4 + 2][r] = v.z; ast[c4 * 4 + 3][r] = v.w;
        float4 wv = *(const float4*)(Bw + (size_t)(col0 + r) * 128 + c4 * 4);
        bst[c4 * 4 + 0][r] = wv.x; bst[c4 * 4 + 1][r] = wv.y;
        bst[c4 * 4 + 2][r] = wv.z; bst[c4 * 4 + 3][r] = wv.w;
    }
    __syncthreads();
    int tx = tid & 15, ty = tid >> 4;
    float acc[4][4];
    #pragma unroll
    for (int j = 0; j < 4; ++j) {
        float bv = bias ? bias[col0 + tx * 4 + j] : 0.f;
        #pragma unroll
        for (int i = 0; i < 4; ++i) acc[i][j] = bv;
    }
    #pragma unroll 4
    for (int k = 0; k < 128; ++k) {
        float4 a = *(const float4*)&ast[k][ty * 4];
        float4 b = *(const float4*)&bst[k][tx * 4];
        float av[4] = {a.x, a.y, a.z, a.w};
        float bv[4] = {b.x, b.y, b.z, b.w};
        #pragma unroll
        for (int i = 0; i < 4; ++i)
            #pragma unroll
            for (int j = 0; j < 4; ++j) acc[i][j] += av[i] * bv[j];
    }
    #pragma unroll
    for (int i = 0; i < 4; ++i) {
        int gr = row0 + ty * 4 + i;
        if (gr >= N) continue;
        float4 o = make_float4(acc[i][0], acc[i][1], acc[i][2], acc[i][3]);
        *(float4*)(out + (size_t)gr * ldo + col0 + tx * 4) = o;
    }
}

// ---------------- Kernel 2: per-(window,head) kv & s reduction ----------------
__global__ __launch_bounds__(256) void k_kv_accum(const float* __restrict__ qkv,
                                                  const int* __restrict__ offsets,
                                                  const int* __restrict__ counts,
                                                  float* __restrict__ kv,
                                                  float* __restrict__ s) {
    int w = blockIdx.x, h = blockIdx.y;
    int tid = threadIdx.x;
    int d = tid >> 4, e = tid & 15;
    __shared__ float kb[16][16];
    __shared__ float vb[16][17];
    int off = offsets[w], cnt = counts[w];
    float acc = 0.f, sacc = 0.f;
    for (int base = 0; base < cnt; base += 16) {
        int pl = tid >> 4, c = tid & 15;
        int p = base + pl;
        float kval = 0.f, vval = 0.f;
        if (p < cnt) {
            const float* row = qkv + (size_t)(off + p) * 384 + h * 16;
            kval = row[128 + c];
            vval = row[256 + c];
        }
        kb[pl][c] = kval > 0.f ? kval : 0.f;
        vb[pl][c] = vval;
        __syncthreads();
        int lim = min(16, cnt - base);
        for (int p2 = 0; p2 < lim; ++p2) {
            float kk = kb[p2][d];
            acc += kk * vb[p2][e];
            if (e == 0) sacc += kk;
        }
        __syncthreads();
    }
    kv[((size_t)(w * HH + h) * 16 + d) * 16 + e] = acc;
    if (e == 0) s[(size_t)(w * HH + h) * 16 + d] = sacc;
}

// ------- Kernel 3a: 3x3 pool of kv with [w,h,d,e] -> [w,h,e,d] transpose -------
__global__ __launch_bounds__(256) void k_pool_kv_t(const float* __restrict__ in,
                                                   float* __restrict__ out) {
    int idx = blockIdx.x * 256 + threadIdx.x;   // over M*H*256, d fastest in OUT
    if (idx >= MWIN * HH * 256) return;
    int d = idx & 15;
    int e = (idx >> 4) & 15;
    int wh = idx >> 8;                 // w*8 + h
    int w = wh >> 3;
    int b = w >> 10, y = (w >> 5) & 31, xx = w & 31;
    float acc = 0.f;
    #pragma unroll
    for (int dy = -1; dy <= 1; ++dy)
        #pragma unroll
        for (int dx = -1; dx <= 1; ++dx) {
            int ny = y + dy, nx = xx + dx;
            if (ny < 0 || ny >= 32 || nx < 0 || nx >= 32) continue;
            int nw = (b << 10) | (ny << 5) | nx;
            acc += in[(((size_t)(nw << 3) | (wh & 7)) << 8) + d * 16 + e];
        }
    out[idx] = acc;   // layout [w][h][e][d]
}

// ------- Kernel 3b: 3x3 pool of s, layout [w,h,d] preserved -------
__global__ __launch_bounds__(256) void k_pool_s(const float* __restrict__ in,
                                                float* __restrict__ out) {
    int idx = blockIdx.x * 256 + threadIdx.x;   // over M*H*16
    if (idx >= MWIN * HH * 16) return;
    int w = idx >> 7;
    int rest = idx & 127;
    int b = w >> 10, y = (w >> 5) & 31, xx = w & 31;
    float acc = 0.f;
    #pragma unroll
    for (int dy = -1; dy <= 1; ++dy)
        #pragma unroll
        for (int dx = -1; dx <= 1; ++dx) {
            int ny = y + dy, nx = xx + dx;
            if (ny < 0 || ny >= 32 || nx < 0 || nx >= 32) continue;
            int nw = (b << 10) | (ny << 5) | nx;
            acc += in[((size_t)nw << 7) + rest];
        }
    out[idx] = acc;
}

// ---------------- Kernel 4: linear attention; y written into qkv's dead k-slice ----
// y[n,h*16+e] = sum_d relu(q[n,h,d]) * kvp_t[w,h,e,d] / (sum_d relu(q)*sp[w,h,d] + 1e-6)
__global__ __launch_bounds__(256) void k_attn(float* __restrict__ qkv,
                                              const float* __restrict__ kvp_t,
                                              const float* __restrict__ sp,
                                              const int* __restrict__ winds, int N) {
    __shared__ float qs[16][128];
    __shared__ float zs[16][8];
    int tid = threadIdx.x;
    int n0 = blockIdx.x * 16;
    // stage relu(q) for 16 points
    for (int it = 0; it < 2; ++it) {
        int li4 = it * 256 + tid;          // float4 id 0..511
        int p = li4 >> 5, c4 = li4 & 31;
        int n = n0 + p;
        float4 v = make_float4(0.f, 0.f, 0.f, 0.f);
        if (n < N) v = *(const float4*)(qkv + (size_t)n * 384 + c4 * 4);
        v.x = v.x > 0.f ? v.x : 0.f; v.y = v.y > 0.f ? v.y : 0.f;
        v.z = v.z > 0.f ? v.z : 0.f; v.w = v.w > 0.f ? v.w : 0.f;
        *(float4*)&qs[p][c4 * 4] = v;
    }
    __syncthreads();
    // z per (point, head)
    if (tid < 128) {
        int p = tid >> 3, h = tid & 7;
        int n = n0 + p;
        float z = 0.f;
        if (n < N) {
            int w = winds[n];
            const float* swp = sp + ((size_t)(w * HH + h) << 4);
            #pragma unroll
            for (int d = 0; d < 16; ++d) z += qs[p][h * 16 + d] * swp[d];
        }
        zs[p][h] = 1.f / (z + 1e-6f);
    }
    __syncthreads();
    // outputs: 2048 values, 8 per thread
    for (int it = 0; it < 8; ++it) {
        int li = it * 256 + tid;
        int p = li >> 7, j = li & 127;
        int n = n0 + p;
        if (n >= N) continue;
        int w = winds[n];
        int h = j >> 4, e = j & 15;
        const float4* kvt = (const float4*)(kvp_t + ((((size_t)(w * HH + h)) << 4) + e) * 16);
        const float4* q4  = (const float4*)&qs[p][h * 16];
        float y = 0.f;
        #pragma unroll
        for (int q = 0; q < 4; ++q) {
            float4 a = q4[q]; float4 b = kvt[q];
            y += a.x * b.x + a.y * b.y + a.z * b.z + a.w * b.w;
        }
        qkv[(size_t)n * 384 + 128 + j] = y * zs[p][h];   // overwrite dead k-slice
    }
}

extern "C" void kernel_launch(void* const* d_in, const int* in_sizes, int n_in,
                              void* d_out, int out_size, void* d_ws, size_t ws_size,
                              hipStream_t stream) {
    const float* x     = (const float*)d_in[0];
    const float* Wqkv  = (const float*)d_in[1];
    const float* Wproj = (const float*)d_in[2];
    const float* bproj = (const float*)d_in[3];
    const int*   offsets = (const int*)d_in[4];
    const int*   counts  = (const int*)d_in[5];
    const int*   winds   = (const int*)d_in[6];

    int N = in_sizes[0] / 128;
    float* ws   = (float*)d_ws;
    float* qkv  = ws;                                   // N*384
    float* kv   = qkv + (size_t)N * 384;                // M*H*256
    float* s    = kv  + (size_t)MWIN * HH * 256;        // M*H*16
    float* kvpt = s   + (size_t)MWIN * HH * 16;         // M*H*256 (transposed e,d)
    float* sp   = kvpt + (size_t)MWIN * HH * 256;       // M*H*16
    float* out  = (float*)d_out;

    dim3 g1((N + 63) / 64, 6);
    k_gemm128<<<g1, 256, 0, stream>>>(x, 128, Wqkv, nullptr, qkv, 384, N);

    dim3 g2(MWIN, HH);
    k_kv_accum<<<g2, 256, 0, stream>>>(qkv, offsets, counts, kv, s);

    int tot_kv = MWIN * HH * 256;
    k_pool_kv_t<<<(tot_kv + 255) / 256, 256, 0, stream>>>(kv, kvpt);
    int tot_s = MWIN * HH * 16;
    k_pool_s<<<(tot_s + 255) / 256, 256, 0, stream>>>(s, sp);

    k_attn<<<(N + 15) / 16, 256, 0, stream>>>(qkv, kvpt, sp, winds, N);

    dim3 g5((N + 63) / 64, 2);
    k_gemm128<<<g5, 256, 0, stream>>>(qkv + 128, 384, Wproj, bproj, out, 128, N);
}

// Round 3
// 302.190 us; speedup vs baseline: 1.8297x; 1.6174x over previous
//
#include <hip/hip_runtime.h>

#define MWIN 2048
#define HH 8

typedef _Float16 half8 __attribute__((ext_vector_type(8)));
typedef float f32x4 __attribute__((ext_vector_type(4)));

// ---------------- fp32 -> fp16 conversion (8 elements/thread) ----------------
__global__ __launch_bounds__(256) void k_cvt(const float* __restrict__ src,
                                             _Float16* __restrict__ dst, int n8) {
    int i = blockIdx.x * 256 + threadIdx.x;
    if (i >= n8) return;
    float4 a = ((const float4*)src)[i * 2];
    float4 b = ((const float4*)src)[i * 2 + 1];
    half8 h;
    h[0] = (_Float16)a.x; h[1] = (_Float16)a.y; h[2] = (_Float16)a.z; h[3] = (_Float16)a.w;
    h[4] = (_Float16)b.x; h[5] = (_Float16)b.y; h[6] = (_Float16)b.z; h[7] = (_Float16)b.w;
    ((half8*)dst)[i] = h;
}

// ---------------- MFMA GEMM, K=128, A/B fp16 K-contiguous, no LDS ----------------
// C[r, col0+c] = sum_k A[r,k] * Bw[c,k] (+bias). Block: 4 waves x 64 rows = 256 rows,
// 64 cols. Wave tile 64x64 via 4x4 grid of 16x16x32 MFMAs.
template <typename OUT_T>
__global__ __launch_bounds__(256) void k_mfma_gemm(const _Float16* __restrict__ A,
                                                   const _Float16* __restrict__ Bw,
                                                   const float* __restrict__ bias,
                                                   OUT_T* __restrict__ out, int ldo, int N) {
    int tid = threadIdx.x;
    int lane = tid & 63, wv = tid >> 6;
    int m = lane & 15, q = lane >> 4;
    int row0 = blockIdx.x * 256 + wv * 64;
    int col0 = blockIdx.y * 64;

    const _Float16* aptr[4];
    const _Float16* bptr[4];
    #pragma unroll
    for (int rt = 0; rt < 4; ++rt) {
        int r = row0 + rt * 16 + m;
        r = r < N ? r : N - 1;
        aptr[rt] = A + (size_t)r * 128 + q * 8;
    }
    #pragma unroll
    for (int ct = 0; ct < 4; ++ct)
        bptr[ct] = Bw + (size_t)(col0 + ct * 16 + m) * 128 + q * 8;

    f32x4 acc[4][4];
    #pragma unroll
    for (int ct = 0; ct < 4; ++ct) {
        float bv = bias ? bias[col0 + ct * 16 + m] : 0.f;
        #pragma unroll
        for (int rt = 0; rt < 4; ++rt)
            acc[rt][ct] = (f32x4){bv, bv, bv, bv};
    }

    #pragma unroll
    for (int ks = 0; ks < 4; ++ks) {
        half8 a[4], b[4];
        #pragma unroll
        for (int rt = 0; rt < 4; ++rt) a[rt] = *(const half8*)(aptr[rt] + ks * 32);
        #pragma unroll
        for (int ct = 0; ct < 4; ++ct) b[ct] = *(const half8*)(bptr[ct] + ks * 32);
        #pragma unroll
        for (int rt = 0; rt < 4; ++rt)
            #pragma unroll
            for (int ct = 0; ct < 4; ++ct)
                acc[rt][ct] = __builtin_amdgcn_mfma_f32_16x16x32_f16(a[rt], b[ct], acc[rt][ct], 0, 0, 0);
    }

    #pragma unroll
    for (int rt = 0; rt < 4; ++rt) {
        #pragma unroll
        for (int reg = 0; reg < 4; ++reg) {
            int row = row0 + rt * 16 + q * 4 + reg;
            if (row >= N) continue;
            #pragma unroll
            for (int ct = 0; ct < 4; ++ct) {
                int col = col0 + ct * 16 + m;
                out[(size_t)row * ldo + col] = (OUT_T)acc[rt][ct][reg];
            }
        }
    }
}

// ---------------- per-(window,head) kv & s reduction (fp16 qkv in, fp32 out) ----
__global__ __launch_bounds__(256) void k_kv_accum(const _Float16* __restrict__ qkv,
                                                  const int* __restrict__ offsets,
                                                  const int* __restrict__ counts,
                                                  float* __restrict__ kv,
                                                  float* __restrict__ s) {
    int w = blockIdx.x, h = blockIdx.y;
    int tid = threadIdx.x;
    int d = tid >> 4, e = tid & 15;
    __shared__ float kb[16][16];
    __shared__ float vb[16][17];
    int off = offsets[w], cnt = counts[w];
    float acc = 0.f, sacc = 0.f;
    for (int base = 0; base < cnt; base += 16) {
        int pl = tid >> 4, c = tid & 15;
        int p = base + pl;
        float kval = 0.f, vval = 0.f;
        if (p < cnt) {
            const _Float16* row = qkv + (size_t)(off + p) * 384 + h * 16;
            kval = (float)row[128 + c];
            vval = (float)row[256 + c];
        }
        kb[pl][c] = kval > 0.f ? kval : 0.f;
        vb[pl][c] = vval;
        __syncthreads();
        int lim = min(16, cnt - base);
        for (int p2 = 0; p2 < lim; ++p2) {
            float kk = kb[p2][d];
            acc += kk * vb[p2][e];
            if (e == 0) sacc += kk;
        }
        __syncthreads();
    }
    kv[((size_t)(w * HH + h) * 16 + d) * 16 + e] = acc;
    if (e == 0) s[(size_t)(w * HH + h) * 16 + d] = sacc;
}

// ------- 3x3 pool of kv with [w,h,d,e] -> [w,h,e,d] transpose -------
__global__ __launch_bounds__(256) void k_pool_kv_t(const float* __restrict__ in,
                                                   float* __restrict__ out) {
    int idx = blockIdx.x * 256 + threadIdx.x;
    if (idx >= MWIN * HH * 256) return;
    int d = idx & 15;
    int e = (idx >> 4) & 15;
    int wh = idx >> 8;
    int w = wh >> 3;
    int b = w >> 10, y = (w >> 5) & 31, xx = w & 31;
    float acc = 0.f;
    #pragma unroll
    for (int dy = -1; dy <= 1; ++dy)
        #pragma unroll
        for (int dx = -1; dx <= 1; ++dx) {
            int ny = y + dy, nx = xx + dx;
            if (ny < 0 || ny >= 32 || nx < 0 || nx >= 32) continue;
            int nw = (b << 10) | (ny << 5) | nx;
            acc += in[(((size_t)(nw << 3) | (wh & 7)) << 8) + d * 16 + e];
        }
    out[idx] = acc;
}

// ------- 3x3 pool of s -------
__global__ __launch_bounds__(256) void k_pool_s(const float* __restrict__ in,
                                                float* __restrict__ out) {
    int idx = blockIdx.x * 256 + threadIdx.x;
    if (idx >= MWIN * HH * 16) return;
    int w = idx >> 7;
    int rest = idx & 127;
    int b = w >> 10, y = (w >> 5) & 31, xx = w & 31;
    float acc = 0.f;
    #pragma unroll
    for (int dy = -1; dy <= 1; ++dy)
        #pragma unroll
        for (int dx = -1; dx <= 1; ++dx) {
            int ny = y + dy, nx = xx + dx;
            if (ny < 0 || ny >= 32 || nx < 0 || nx >= 32) continue;
            int nw = (b << 10) | (ny << 5) | nx;
            acc += in[((size_t)nw << 7) + rest];
        }
    out[idx] = acc;
}

// ---------------- linear attention; q fp16 in, y fp16 out ----------------
__global__ __launch_bounds__(256) void k_attn(const _Float16* __restrict__ qkv,
                                              const float* __restrict__ kvp_t,
                                              const float* __restrict__ sp,
                                              const int* __restrict__ winds,
                                              _Float16* __restrict__ y_h, int N) {
    __shared__ float qs[16][128];
    __shared__ float zs[16][8];
    int tid = threadIdx.x;
    int n0 = blockIdx.x * 16;
    // stage relu(q) for 16 points: 2048 elements, one half8 per thread
    {
        int p = tid >> 4, c8 = tid & 15;
        int n = n0 + p;
        float v[8];
        if (n < N) {
            half8 hv = *(const half8*)(qkv + (size_t)n * 384 + c8 * 8);
            #pragma unroll
            for (int j = 0; j < 8; ++j) {
                float f = (float)hv[j];
                v[j] = f > 0.f ? f : 0.f;
            }
        } else {
            #pragma unroll
            for (int j = 0; j < 8; ++j) v[j] = 0.f;
        }
        #pragma unroll
        for (int j = 0; j < 8; ++j) qs[p][c8 * 8 + j] = v[j];
    }
    __syncthreads();
    if (tid < 128) {
        int p = tid >> 3, h = tid & 7;
        int n = n0 + p;
        float z = 0.f;
        if (n < N) {
            int w = winds[n];
            const float* swp = sp + ((size_t)(w * HH + h) << 4);
            #pragma unroll
            for (int d = 0; d < 16; ++d) z += qs[p][h * 16 + d] * swp[d];
        }
        zs[p][h] = 1.f / (z + 1e-6f);
    }
    __syncthreads();
    for (int it = 0; it < 8; ++it) {
        int li = it * 256 + tid;
        int p = li >> 7, j = li & 127;
        int n = n0 + p;
        if (n >= N) continue;
        int w = winds[n];
        int h = j >> 4, e = j & 15;
        const float4* kvt = (const float4*)(kvp_t + ((((size_t)(w * HH + h)) << 4) + e) * 16);
        const float4* q4  = (const float4*)&qs[p][h * 16];
        float y = 0.f;
        #pragma unroll
        for (int qq = 0; qq < 4; ++qq) {
            float4 a = q4[qq]; float4 b = kvt[qq];
            y += a.x * b.x + a.y * b.y + a.z * b.z + a.w * b.w;
        }
        y_h[(size_t)n * 128 + j] = (_Float16)(y * zs[p][h]);
    }
}

extern "C" void kernel_launch(void* const* d_in, const int* in_sizes, int n_in,
                              void* d_out, int out_size, void* d_ws, size_t ws_size,
                              hipStream_t stream) {
    const float* x     = (const float*)d_in[0];
    const float* Wqkv  = (const float*)d_in[1];
    const float* Wproj = (const float*)d_in[2];
    const float* bproj = (const float*)d_in[3];
    const int*   offsets = (const int*)d_in[4];
    const int*   counts  = (const int*)d_in[5];
    const int*   winds   = (const int*)d_in[6];

    int N = in_sizes[0] / 128;

    // workspace layout (bytes, all 16B-aligned)
    char* ws = (char*)d_ws;
    float* kv   = (float*)ws;                                    ws += (size_t)MWIN * HH * 256 * 4;
    float* s    = (float*)ws;                                    ws += (size_t)MWIN * HH * 16 * 4;
    float* kvpt = (float*)ws;                                    ws += (size_t)MWIN * HH * 256 * 4;
    float* sp   = (float*)ws;                                    ws += (size_t)MWIN * HH * 16 * 4;
    _Float16* x_h    = (_Float16*)ws;                            ws += (size_t)N * 128 * 2;
    _Float16* qkv_h  = (_Float16*)ws;                            ws += (size_t)N * 384 * 2;
    _Float16* y_h    = (_Float16*)ws;                            ws += (size_t)N * 128 * 2;
    _Float16* Wqkv_h = (_Float16*)ws;                            ws += (size_t)384 * 128 * 2;
    _Float16* Wp_h   = (_Float16*)ws;                            ws += (size_t)128 * 128 * 2;
    float* out  = (float*)d_out;

    int n8x = N * 128 / 8;
    k_cvt<<<(n8x + 255) / 256, 256, 0, stream>>>(x, x_h, n8x);
    k_cvt<<<(384 * 128 / 8 + 255) / 256, 256, 0, stream>>>(Wqkv, Wqkv_h, 384 * 128 / 8);
    k_cvt<<<(128 * 128 / 8 + 255) / 256, 256, 0, stream>>>(Wproj, Wp_h, 128 * 128 / 8);

    dim3 g1((N + 255) / 256, 6);
    k_mfma_gemm<_Float16><<<g1, 256, 0, stream>>>(x_h, Wqkv_h, nullptr, qkv_h, 384, N);

    dim3 g2(MWIN, HH);
    k_kv_accum<<<g2, 256, 0, stream>>>(qkv_h, offsets, counts, kv, s);

    int tot_kv = MWIN * HH * 256;
    k_pool_kv_t<<<(tot_kv + 255) / 256, 256, 0, stream>>>(kv, kvpt);
    int tot_s = MWIN * HH * 16;
    k_pool_s<<<(tot_s + 255) / 256, 256, 0, stream>>>(s, sp);

    k_attn<<<(N + 15) / 16, 256, 0, stream>>>(qkv_h, kvpt, sp, winds, y_h, N);

    dim3 g5((N + 255) / 256, 2);
    k_mfma_gemm<float><<<g5, 256, 0, stream>>>(y_h, Wp_h, bproj, out, 128, N);
}

// Round 4
// 246.626 us; speedup vs baseline: 2.2419x; 1.2253x over previous
//
#include <hip/hip_runtime.h>

#define MWIN 2048
#define HH 8

typedef _Float16 half8 __attribute__((ext_vector_type(8)));
typedef float f32x4 __attribute__((ext_vector_type(4)));

// ---------------- fp32 -> fp16 conversion (8 elements/thread) ----------------
__global__ __launch_bounds__(256) void k_cvt(const float* __restrict__ src,
                                             _Float16* __restrict__ dst, int n8) {
    int i = blockIdx.x * 256 + threadIdx.x;
    if (i >= n8) return;
    float4 a = ((const float4*)src)[i * 2];
    float4 b = ((const float4*)src)[i * 2 + 1];
    half8 h;
    h[0] = (_Float16)a.x; h[1] = (_Float16)a.y; h[2] = (_Float16)a.z; h[3] = (_Float16)a.w;
    h[4] = (_Float16)b.x; h[5] = (_Float16)b.y; h[6] = (_Float16)b.z; h[7] = (_Float16)b.w;
    ((half8*)dst)[i] = h;
}

// ---------------- MFMA GEMM, K=128, A/B fp16 K-contiguous, no LDS ----------------
template <typename OUT_T>
__global__ __launch_bounds__(256) void k_mfma_gemm(const _Float16* __restrict__ A,
                                                   const _Float16* __restrict__ Bw,
                                                   const float* __restrict__ bias,
                                                   OUT_T* __restrict__ out, int ldo, int N) {
    int tid = threadIdx.x;
    int lane = tid & 63, wv = tid >> 6;
    int m = lane & 15, q = lane >> 4;
    int row0 = blockIdx.x * 256 + wv * 64;
    int col0 = blockIdx.y * 64;

    const _Float16* aptr[4];
    const _Float16* bptr[4];
    #pragma unroll
    for (int rt = 0; rt < 4; ++rt) {
        int r = row0 + rt * 16 + m;
        r = r < N ? r : N - 1;
        aptr[rt] = A + (size_t)r * 128 + q * 8;
    }
    #pragma unroll
    for (int ct = 0; ct < 4; ++ct)
        bptr[ct] = Bw + (size_t)(col0 + ct * 16 + m) * 128 + q * 8;

    f32x4 acc[4][4];
    #pragma unroll
    for (int ct = 0; ct < 4; ++ct) {
        float bv = bias ? bias[col0 + ct * 16 + m] : 0.f;
        #pragma unroll
        for (int rt = 0; rt < 4; ++rt)
            acc[rt][ct] = (f32x4){bv, bv, bv, bv};
    }

    #pragma unroll
    for (int ks = 0; ks < 4; ++ks) {
        half8 a[4], b[4];
        #pragma unroll
        for (int rt = 0; rt < 4; ++rt) a[rt] = *(const half8*)(aptr[rt] + ks * 32);
        #pragma unroll
        for (int ct = 0; ct < 4; ++ct) b[ct] = *(const half8*)(bptr[ct] + ks * 32);
        #pragma unroll
        for (int rt = 0; rt < 4; ++rt)
            #pragma unroll
            for (int ct = 0; ct < 4; ++ct)
                acc[rt][ct] = __builtin_amdgcn_mfma_f32_16x16x32_f16(a[rt], b[ct], acc[rt][ct], 0, 0, 0);
    }

    #pragma unroll
    for (int rt = 0; rt < 4; ++rt) {
        #pragma unroll
        for (int reg = 0; reg < 4; ++reg) {
            int row = row0 + rt * 16 + q * 4 + reg;
            if (row >= N) continue;
            #pragma unroll
            for (int ct = 0; ct < 4; ++ct) {
                int col = col0 + ct * 16 + m;
                out[(size_t)row * ldo + col] = (OUT_T)acc[rt][ct][reg];
            }
        }
    }
}

// ---- per-(window,head) kv & s reduction; kv written TRANSPOSED [w,h,e,d] ----
// thread tid: d = tid&15, e = tid>>4  ->  out offset e*16+d == tid (coalesced)
__global__ __launch_bounds__(256) void k_kv_accum(const _Float16* __restrict__ qkv,
                                                  const int* __restrict__ offsets,
                                                  const int* __restrict__ counts,
                                                  float* __restrict__ kv_t,
                                                  float* __restrict__ s) {
    int w = blockIdx.x, h = blockIdx.y;
    int tid = threadIdx.x;
    int d = tid & 15, e = tid >> 4;
    __shared__ float kb[32][16];
    __shared__ float vb[32][16];
    int off = offsets[w], cnt = counts[w];
    float acc = 0.f, sacc = 0.f;
    for (int base = 0; base < cnt; base += 32) {
        int pl = tid >> 3, c2 = tid & 7;     // point-lane 0..31, half2 id 0..7
        int p = base + pl;
        float k0 = 0.f, k1 = 0.f, v0 = 0.f, v1 = 0.f;
        if (p < cnt) {
            const _Float16* row = qkv + (size_t)(off + p) * 384 + h * 16 + c2 * 2;
            k0 = (float)row[128]; k1 = (float)row[129];
            v0 = (float)row[256]; v1 = (float)row[257];
        }
        kb[pl][c2 * 2]     = k0 > 0.f ? k0 : 0.f;
        kb[pl][c2 * 2 + 1] = k1 > 0.f ? k1 : 0.f;
        vb[pl][c2 * 2]     = v0;
        vb[pl][c2 * 2 + 1] = v1;
        __syncthreads();
        int lim = min(32, cnt - base);
        for (int p2 = 0; p2 < lim; ++p2) {
            float kk = kb[p2][d];
            acc += kk * vb[p2][e];
            if (e == 0) sacc += kk;
        }
        __syncthreads();
    }
    kv_t[((size_t)(w * HH + h) << 8) + tid] = acc;       // [w][h][e][d]
    if (e == 0) s[((size_t)(w * HH + h) << 4) + d] = sacc;
}

// ------- fused 3x3 pool: kv_t (layout-preserving) + s, float4-vectorized -------
#define KV4 (MWIN * 512)   // float4 count of kv_t
#define S4  (MWIN * 32)    // float4 count of s
__global__ __launch_bounds__(256) void k_pool_all(const float* __restrict__ kv_in,
                                                  float* __restrict__ kv_out,
                                                  const float* __restrict__ s_in,
                                                  float* __restrict__ s_out) {
    int idx = blockIdx.x * 256 + threadIdx.x;
    const float* in;
    float* outp;
    int w, rest, shift;
    if (idx < KV4) {
        w = idx >> 9; rest = idx & 511; shift = 9;
        in = kv_in; outp = kv_out;
    } else {
        int j = idx - KV4;
        if (j >= S4) return;
        w = j >> 5; rest = j & 31; shift = 5;
        in = s_in; outp = s_out;
        idx = j;
    }
    int b = w >> 10, y = (w >> 5) & 31, xx = w & 31;
    f32x4 acc = {0.f, 0.f, 0.f, 0.f};
    #pragma unroll
    for (int dy = -1; dy <= 1; ++dy)
        #pragma unroll
        for (int dx = -1; dx <= 1; ++dx) {
            int ny = y + dy, nx = xx + dx;
            if (ny < 0 || ny >= 32 || nx < 0 || nx >= 32) continue;
            int nw = (b << 10) | (ny << 5) | nx;
            f32x4 v = ((const f32x4*)in)[((size_t)nw << shift) + rest];
            acc += v;
        }
    ((f32x4*)outp)[idx] = acc;
}

// ---------------- linear attention; q fp16 in, y fp16 out ----------------
__global__ __launch_bounds__(256) void k_attn(const _Float16* __restrict__ qkv,
                                              const float* __restrict__ kvp_t,
                                              const float* __restrict__ sp,
                                              const int* __restrict__ winds,
                                              _Float16* __restrict__ y_h, int N) {
    __shared__ float qs[16][128];
    __shared__ float zs[16][8];
    int tid = threadIdx.x;
    int n0 = blockIdx.x * 16;
    {
        int p = tid >> 4, c8 = tid & 15;
        int n = n0 + p;
        float v[8];
        if (n < N) {
            half8 hv = *(const half8*)(qkv + (size_t)n * 384 + c8 * 8);
            #pragma unroll
            for (int j = 0; j < 8; ++j) {
                float f = (float)hv[j];
                v[j] = f > 0.f ? f : 0.f;
            }
        } else {
            #pragma unroll
            for (int j = 0; j < 8; ++j) v[j] = 0.f;
        }
        #pragma unroll
        for (int j = 0; j < 8; ++j) qs[p][c8 * 8 + j] = v[j];
    }
    __syncthreads();
    if (tid < 128) {
        int p = tid >> 3, h = tid & 7;
        int n = n0 + p;
        float z = 0.f;
        if (n < N) {
            int w = winds[n];
            const float* swp = sp + ((size_t)(w * HH + h) << 4);
            #pragma unroll
            for (int d = 0; d < 16; ++d) z += qs[p][h * 16 + d] * swp[d];
        }
        zs[p][h] = 1.f / (z + 1e-6f);
    }
    __syncthreads();
    for (int it = 0; it < 8; ++it) {
        int li = it * 256 + tid;
        int p = li >> 7, j = li & 127;
        int n = n0 + p;
        if (n >= N) continue;
        int w = winds[n];
        int h = j >> 4, e = j & 15;
        const float4* kvt = (const float4*)(kvp_t + ((((size_t)(w * HH + h)) << 4) + e) * 16);
        const float4* q4  = (const float4*)&qs[p][h * 16];
        float y = 0.f;
        #pragma unroll
        for (int qq = 0; qq < 4; ++qq) {
            float4 a = q4[qq]; float4 b = kvt[qq];
            y += a.x * b.x + a.y * b.y + a.z * b.z + a.w * b.w;
        }
        y_h[(size_t)n * 128 + j] = (_Float16)(y * zs[p][h]);
    }
}

extern "C" void kernel_launch(void* const* d_in, const int* in_sizes, int n_in,
                              void* d_out, int out_size, void* d_ws, size_t ws_size,
                              hipStream_t stream) {
    const float* x     = (const float*)d_in[0];
    const float* Wqkv  = (const float*)d_in[1];
    const float* Wproj = (const float*)d_in[2];
    const float* bproj = (const float*)d_in[3];
    const int*   offsets = (const int*)d_in[4];
    const int*   counts  = (const int*)d_in[5];
    const int*   winds   = (const int*)d_in[6];

    int N = in_sizes[0] / 128;

    char* ws = (char*)d_ws;
    float* kv_t = (float*)ws;                                    ws += (size_t)MWIN * HH * 256 * 4;
    float* s    = (float*)ws;                                    ws += (size_t)MWIN * HH * 16 * 4;
    float* kvpt = (float*)ws;                                    ws += (size_t)MWIN * HH * 256 * 4;
    float* sp   = (float*)ws;                                    ws += (size_t)MWIN * HH * 16 * 4;
    _Float16* x_h    = (_Float16*)ws;                            ws += (size_t)N * 128 * 2;
    _Float16* qkv_h  = (_Float16*)ws;                            ws += (size_t)N * 384 * 2;
    _Float16* y_h    = (_Float16*)ws;                            ws += (size_t)N * 128 * 2;
    _Float16* Wqkv_h = (_Float16*)ws;                            ws += (size_t)384 * 128 * 2;
    _Float16* Wp_h   = (_Float16*)ws;                            ws += (size_t)128 * 128 * 2;
    float* out  = (float*)d_out;

    int n8x = N * 128 / 8;
    k_cvt<<<(n8x + 255) / 256, 256, 0, stream>>>(x, x_h, n8x);
    k_cvt<<<(384 * 128 / 8 + 255) / 256, 256, 0, stream>>>(Wqkv, Wqkv_h, 384 * 128 / 8);
    k_cvt<<<(128 * 128 / 8 + 255) / 256, 256, 0, stream>>>(Wproj, Wp_h, 128 * 128 / 8);

    dim3 g1((N + 255) / 256, 6);
    k_mfma_gemm<_Float16><<<g1, 256, 0, stream>>>(x_h, Wqkv_h, nullptr, qkv_h, 384, N);

    dim3 g2(MWIN, HH);
    k_kv_accum<<<g2, 256, 0, stream>>>(qkv_h, offsets, counts, kv_t, s);

    k_pool_all<<<(KV4 + S4 + 255) / 256, 256, 0, stream>>>(kv_t, kvpt, s, sp);

    k_attn<<<(N + 15) / 16, 256, 0, stream>>>(qkv_h, kvpt, sp, winds, y_h, N);

    dim3 g5((N + 255) / 256, 2);
    k_mfma_gemm<float><<<g5, 256, 0, stream>>>(y_h, Wp_h, bproj, out, 128, N);
}

// Round 5
// 226.565 us; speedup vs baseline: 2.4404x; 1.0885x over previous
//
#include <hip/hip_runtime.h>

#define MWIN 2048
#define HH 8

typedef _Float16 half8 __attribute__((ext_vector_type(8)));
typedef _Float16 half4 __attribute__((ext_vector_type(4)));
typedef float f32x4 __attribute__((ext_vector_type(4)));

// ---------------- fp32 -> fp16 conversion (8 elements/thread) ----------------
__global__ __launch_bounds__(256) void k_cvt(const float* __restrict__ src,
                                             _Float16* __restrict__ dst, int n8) {
    int i = blockIdx.x * 256 + threadIdx.x;
    if (i >= n8) return;
    float4 a = ((const float4*)src)[i * 2];
    float4 b = ((const float4*)src)[i * 2 + 1];
    half8 h;
    h[0] = (_Float16)a.x; h[1] = (_Float16)a.y; h[2] = (_Float16)a.z; h[3] = (_Float16)a.w;
    h[4] = (_Float16)b.x; h[5] = (_Float16)b.y; h[6] = (_Float16)b.z; h[7] = (_Float16)b.w;
    ((half8*)dst)[i] = h;
}

// ---------------- MFMA GEMM, K=128, A/B fp16 K-contiguous, no LDS ----------------
template <typename OUT_T>
__global__ __launch_bounds__(256) void k_mfma_gemm(const _Float16* __restrict__ A,
                                                   const _Float16* __restrict__ Bw,
                                                   const float* __restrict__ bias,
                                                   OUT_T* __restrict__ out, int ldo, int N) {
    int tid = threadIdx.x;
    int lane = tid & 63, wv = tid >> 6;
    int m = lane & 15, q = lane >> 4;
    int row0 = blockIdx.x * 256 + wv * 64;
    int col0 = blockIdx.y * 64;

    const _Float16* aptr[4];
    const _Float16* bptr[4];
    #pragma unroll
    for (int rt = 0; rt < 4; ++rt) {
        int r = row0 + rt * 16 + m;
        r = r < N ? r : N - 1;
        aptr[rt] = A + (size_t)r * 128 + q * 8;
    }
    #pragma unroll
    for (int ct = 0; ct < 4; ++ct)
        bptr[ct] = Bw + (size_t)(col0 + ct * 16 + m) * 128 + q * 8;

    f32x4 acc[4][4];
    #pragma unroll
    for (int ct = 0; ct < 4; ++ct) {
        float bv = bias ? bias[col0 + ct * 16 + m] : 0.f;
        #pragma unroll
        for (int rt = 0; rt < 4; ++rt)
            acc[rt][ct] = (f32x4){bv, bv, bv, bv};
    }

    #pragma unroll
    for (int ks = 0; ks < 4; ++ks) {
        half8 a[4], b[4];
        #pragma unroll
        for (int rt = 0; rt < 4; ++rt) a[rt] = *(const half8*)(aptr[rt] + ks * 32);
        #pragma unroll
        for (int ct = 0; ct < 4; ++ct) b[ct] = *(const half8*)(bptr[ct] + ks * 32);
        #pragma unroll
        for (int rt = 0; rt < 4; ++rt)
            #pragma unroll
            for (int ct = 0; ct < 4; ++ct)
                acc[rt][ct] = __builtin_amdgcn_mfma_f32_16x16x32_f16(a[rt], b[ct], acc[rt][ct], 0, 0, 0);
    }

    #pragma unroll
    for (int rt = 0; rt < 4; ++rt) {
        #pragma unroll
        for (int reg = 0; reg < 4; ++reg) {
            int row = row0 + rt * 16 + q * 4 + reg;
            if (row >= N) continue;
            #pragma unroll
            for (int ct = 0; ct < 4; ++ct) {
                int col = col0 + ct * 16 + m;
                out[(size_t)row * ldo + col] = (OUT_T)acc[rt][ct][reg];
            }
        }
    }
}

// ---- per-(window,head) kv & s reduction; wave per (w, 2h), no LDS/barriers ----
// lane: d = lane&15, eq = lane>>4; computes kv_t[w][h][e=eq*4+j][d] and s[w][h][d]
__global__ __launch_bounds__(256) void k_kv_accum(const _Float16* __restrict__ qkv,
                                                  const int* __restrict__ offsets,
                                                  const int* __restrict__ counts,
                                                  float* __restrict__ kv_t,
                                                  float* __restrict__ s) {
    int w = blockIdx.x;
    int wv = threadIdx.x >> 6, lane = threadIdx.x & 63;
    int d = lane & 15, eq = lane >> 4;
    int off = offsets[w], cnt = counts[w];
    #pragma unroll
    for (int hh = 0; hh < 2; ++hh) {
        int h = wv * 2 + hh;
        float acc0 = 0.f, acc1 = 0.f, acc2 = 0.f, acc3 = 0.f, sacc = 0.f;
        const _Float16* base = qkv + (size_t)off * 384 + h * 16;
        for (int p = 0; p < cnt; ++p) {
            const _Float16* row = base + (size_t)p * 384;
            float kk = (float)row[128 + d];
            kk = kk > 0.f ? kk : 0.f;
            half4 v4 = *(const half4*)(row + 256 + eq * 4);
            acc0 += kk * (float)v4[0];
            acc1 += kk * (float)v4[1];
            acc2 += kk * (float)v4[2];
            acc3 += kk * (float)v4[3];
            sacc += kk;
        }
        float* o = kv_t + (((size_t)(w * HH + h)) << 8);
        o[(eq * 4 + 0) * 16 + d] = acc0;
        o[(eq * 4 + 1) * 16 + d] = acc1;
        o[(eq * 4 + 2) * 16 + d] = acc2;
        o[(eq * 4 + 3) * 16 + d] = acc3;
        if (eq == 0) s[(((size_t)(w * HH + h)) << 4) + d] = sacc;
    }
}

// ------- fused 3x3 pool: fp32 in -> fp16 out, float4-granular -------
#define KV4 (MWIN * 512)   // float4 count of kv_t
#define S4  (MWIN * 32)    // float4 count of s
__global__ __launch_bounds__(256) void k_pool_all(const float* __restrict__ kv_in,
                                                  _Float16* __restrict__ kv_out,
                                                  const float* __restrict__ s_in,
                                                  _Float16* __restrict__ s_out) {
    int idx = blockIdx.x * 256 + threadIdx.x;
    const float* in;
    _Float16* outp;
    int w, rest, shift;
    if (idx < KV4) {
        w = idx >> 9; rest = idx & 511; shift = 9;
        in = kv_in; outp = kv_out;
    } else {
        int j = idx - KV4;
        if (j >= S4) return;
        w = j >> 5; rest = j & 31; shift = 5;
        in = s_in; outp = s_out;
        idx = j;
    }
    int b = w >> 10, y = (w >> 5) & 31, xx = w & 31;
    f32x4 acc = {0.f, 0.f, 0.f, 0.f};
    #pragma unroll
    for (int dy = -1; dy <= 1; ++dy)
        #pragma unroll
        for (int dx = -1; dx <= 1; ++dx) {
            int ny = y + dy, nx = xx + dx;
            if (ny < 0 || ny >= 32 || nx < 0 || nx >= 32) continue;
            int nw = (b << 10) | (ny << 5) | nx;
            f32x4 v = ((const f32x4*)in)[((size_t)nw << shift) + rest];
            acc += v;
        }
    half4 hv;
    hv[0] = (_Float16)acc[0]; hv[1] = (_Float16)acc[1];
    hv[2] = (_Float16)acc[2]; hv[3] = (_Float16)acc[3];
    ((half4*)outp)[idx] = hv;
}

// ---------------- linear attention: one wave per window, MFMA-based ----------------
// D_kv[e][p] = sum_d kv[h,e,d]*relu(q[p,h,d]);  D_s[*][p] = z[p]
__global__ __launch_bounds__(256) void k_attn(const _Float16* __restrict__ qkv,
                                              const _Float16* __restrict__ kvp,
                                              const _Float16* __restrict__ sp,
                                              const int* __restrict__ offsets,
                                              const int* __restrict__ counts,
                                              _Float16* __restrict__ y_h) {
    int w = blockIdx.x * 4 + (threadIdx.x >> 6);
    int lane = threadIdx.x & 63;
    int col = lane & 15;        // A row m=e, B col n=p, D col p
    int kq = lane >> 4;         // k-group
    int off = offsets[w], cnt = counts[w];
    bool klive = kq < 2;        // K=32 MFMA, only k<16 is real
    int koff = (kq & 1) * 8;
    half8 zf = {};
    for (int h = 0; h < 8; ++h) {
        half8 t = *(const half8*)(kvp + ((((size_t)(w * HH + h)) << 8) + col * 16 + koff));
        half8 a_kv = klive ? t : zf;
        half8 t2 = *(const half8*)(sp + ((((size_t)(w * HH + h)) << 4) + koff));
        half8 a_s = klive ? t2 : zf;
        #pragma unroll
        for (int c = 0; c < 3; ++c) {
            int p = c * 16 + col;
            int pc = p < cnt ? p : cnt - 1;
            half8 qv = *(const half8*)(qkv + (size_t)(off + pc) * 384 + h * 16 + koff);
            #pragma unroll
            for (int i = 0; i < 8; ++i) qv[i] = qv[i] > (_Float16)0 ? qv[i] : (_Float16)0;
            half8 b_q = klive ? qv : zf;
            f32x4 acc = {};
            acc = __builtin_amdgcn_mfma_f32_16x16x32_f16(a_kv, b_q, acc, 0, 0, 0);
            f32x4 accs = {};
            accs = __builtin_amdgcn_mfma_f32_16x16x32_f16(a_s, b_q, accs, 0, 0, 0);
            float zinv = 1.f / (accs[0] + 1e-6f);
            half4 yo;
            #pragma unroll
            for (int i = 0; i < 4; ++i) yo[i] = (_Float16)(acc[i] * zinv);
            if (p < cnt)
                *(half4*)(y_h + (size_t)(off + p) * 128 + h * 16 + kq * 4) = yo;
        }
    }
}

extern "C" void kernel_launch(void* const* d_in, const int* in_sizes, int n_in,
                              void* d_out, int out_size, void* d_ws, size_t ws_size,
                              hipStream_t stream) {
    const float* x     = (const float*)d_in[0];
    const float* Wqkv  = (const float*)d_in[1];
    const float* Wproj = (const float*)d_in[2];
    const float* bproj = (const float*)d_in[3];
    const int*   offsets = (const int*)d_in[4];
    const int*   counts  = (const int*)d_in[5];

    int N = in_sizes[0] / 128;

    char* ws = (char*)d_ws;
    float* kv_t = (float*)ws;                                    ws += (size_t)MWIN * HH * 256 * 4;
    float* s    = (float*)ws;                                    ws += (size_t)MWIN * HH * 16 * 4;
    _Float16* kvpt = (_Float16*)ws;                              ws += (size_t)MWIN * HH * 256 * 2;
    _Float16* sp   = (_Float16*)ws;                              ws += (size_t)MWIN * HH * 16 * 2;
    _Float16* x_h    = (_Float16*)ws;                            ws += (size_t)N * 128 * 2;
    _Float16* qkv_h  = (_Float16*)ws;                            ws += (size_t)N * 384 * 2;
    _Float16* y_h    = (_Float16*)ws;                            ws += (size_t)N * 128 * 2;
    _Float16* Wqkv_h = (_Float16*)ws;                            ws += (size_t)384 * 128 * 2;
    _Float16* Wp_h   = (_Float16*)ws;                            ws += (size_t)128 * 128 * 2;
    float* out  = (float*)d_out;

    int n8x = N * 128 / 8;
    k_cvt<<<(n8x + 255) / 256, 256, 0, stream>>>(x, x_h, n8x);
    k_cvt<<<(384 * 128 / 8 + 255) / 256, 256, 0, stream>>>(Wqkv, Wqkv_h, 384 * 128 / 8);
    k_cvt<<<(128 * 128 / 8 + 255) / 256, 256, 0, stream>>>(Wproj, Wp_h, 128 * 128 / 8);

    dim3 g1((N + 255) / 256, 6);
    k_mfma_gemm<_Float16><<<g1, 256, 0, stream>>>(x_h, Wqkv_h, nullptr, qkv_h, 384, N);

    k_kv_accum<<<MWIN, 256, 0, stream>>>(qkv_h, offsets, counts, kv_t, s);

    k_pool_all<<<(KV4 + S4 + 255) / 256, 256, 0, stream>>>(kv_t, kvpt, s, sp);

    k_attn<<<MWIN / 4, 256, 0, stream>>>(qkv_h, kvpt, sp, offsets, counts, y_h);

    dim3 g5((N + 255) / 256, 2);
    k_mfma_gemm<float><<<g5, 256, 0, stream>>>(y_h, Wp_h, bproj, out, 128, N);
}

// Round 6
// 220.678 us; speedup vs baseline: 2.5055x; 1.0267x over previous
//
#include <hip/hip_runtime.h>

#define MWIN 2048
#define HH 8

typedef _Float16 half8 __attribute__((ext_vector_type(8)));
typedef _Float16 half4 __attribute__((ext_vector_type(4)));
typedef float f32x4 __attribute__((ext_vector_type(4)));

// ---------------- fp32 -> fp16 conversion (8 elements/thread) ----------------
__global__ __launch_bounds__(256) void k_cvt(const float* __restrict__ src,
                                             _Float16* __restrict__ dst, int n8) {
    int i = blockIdx.x * 256 + threadIdx.x;
    if (i >= n8) return;
    float4 a = ((const float4*)src)[i * 2];
    float4 b = ((const float4*)src)[i * 2 + 1];
    half8 h;
    h[0] = (_Float16)a.x; h[1] = (_Float16)a.y; h[2] = (_Float16)a.z; h[3] = (_Float16)a.w;
    h[4] = (_Float16)b.x; h[5] = (_Float16)b.y; h[6] = (_Float16)b.z; h[7] = (_Float16)b.w;
    ((half8*)dst)[i] = h;
}

// ---- MFMA GEMM, K=128: A-tile loaded ONCE per block, loop over ncg 64-col groups ----
// Block: 4 waves x 64 rows = 256 rows. Wave tile 64x64 per column group.
template <typename OUT_T>
__global__ __launch_bounds__(256) void k_mfma_gemm(const _Float16* __restrict__ A,
                                                   const _Float16* __restrict__ Bw,
                                                   const float* __restrict__ bias,
                                                   OUT_T* __restrict__ out, int ldo,
                                                   int N, int ncg) {
    int tid = threadIdx.x;
    int lane = tid & 63, wv = tid >> 6;
    int m = lane & 15, q = lane >> 4;
    int row0 = blockIdx.x * 256 + wv * 64;

    // A fragments: 4 row-tiles x 4 k-steps, held for the whole kernel
    half8 a[4][4];
    #pragma unroll
    for (int rt = 0; rt < 4; ++rt) {
        int r = row0 + rt * 16 + m;
        r = r < N ? r : N - 1;
        const _Float16* ap = A + (size_t)r * 128 + q * 8;
        #pragma unroll
        for (int ks = 0; ks < 4; ++ks) a[rt][ks] = *(const half8*)(ap + ks * 32);
    }

    for (int cg = 0; cg < ncg; ++cg) {
        int col0 = cg * 64;
        f32x4 acc[4][4];
        #pragma unroll
        for (int ct = 0; ct < 4; ++ct) {
            float bv = bias ? bias[col0 + ct * 16 + m] : 0.f;
            #pragma unroll
            for (int rt = 0; rt < 4; ++rt) acc[rt][ct] = (f32x4){bv, bv, bv, bv};
        }
        #pragma unroll
        for (int ks = 0; ks < 4; ++ks) {
            half8 b[4];
            #pragma unroll
            for (int ct = 0; ct < 4; ++ct)
                b[ct] = *(const half8*)(Bw + (size_t)(col0 + ct * 16 + m) * 128 + q * 8 + ks * 32);
            #pragma unroll
            for (int rt = 0; rt < 4; ++rt)
                #pragma unroll
                for (int ct = 0; ct < 4; ++ct)
                    acc[rt][ct] = __builtin_amdgcn_mfma_f32_16x16x32_f16(a[rt][ks], b[ct], acc[rt][ct], 0, 0, 0);
        }
        #pragma unroll
        for (int rt = 0; rt < 4; ++rt) {
            #pragma unroll
            for (int reg = 0; reg < 4; ++reg) {
                int row = row0 + rt * 16 + q * 4 + reg;
                if (row >= N) continue;
                #pragma unroll
                for (int ct = 0; ct < 4; ++ct)
                    out[(size_t)row * ldo + col0 + ct * 16 + m] = (OUT_T)acc[rt][ct][reg];
            }
        }
    }
}

// ---- per-(window,head) kv & s reduction; wave per (w, 2h), no LDS/barriers ----
__global__ __launch_bounds__(256) void k_kv_accum(const _Float16* __restrict__ qkv,
                                                  const int* __restrict__ offsets,
                                                  const int* __restrict__ counts,
                                                  float* __restrict__ kv_t,
                                                  float* __restrict__ s) {
    int w = blockIdx.x;
    int wv = threadIdx.x >> 6, lane = threadIdx.x & 63;
    int d = lane & 15, eq = lane >> 4;
    int off = offsets[w], cnt = counts[w];
    #pragma unroll
    for (int hh = 0; hh < 2; ++hh) {
        int h = wv * 2 + hh;
        float acc0 = 0.f, acc1 = 0.f, acc2 = 0.f, acc3 = 0.f, sacc = 0.f;
        const _Float16* base = qkv + (size_t)off * 384 + h * 16;
        for (int p = 0; p < cnt; ++p) {
            const _Float16* row = base + (size_t)p * 384;
            float kk = (float)row[128 + d];
            kk = kk > 0.f ? kk : 0.f;
            half4 v4 = *(const half4*)(row + 256 + eq * 4);
            acc0 += kk * (float)v4[0];
            acc1 += kk * (float)v4[1];
            acc2 += kk * (float)v4[2];
            acc3 += kk * (float)v4[3];
            sacc += kk;
        }
        float* o = kv_t + (((size_t)(w * HH + h)) << 8);
        o[(eq * 4 + 0) * 16 + d] = acc0;
        o[(eq * 4 + 1) * 16 + d] = acc1;
        o[(eq * 4 + 2) * 16 + d] = acc2;
        o[(eq * 4 + 3) * 16 + d] = acc3;
        if (eq == 0) s[(((size_t)(w * HH + h)) << 4) + d] = sacc;
    }
}

// ------- fused 3x3 pool: fp32 in -> fp16 out, float4-granular -------
#define KV4 (MWIN * 512)
#define S4  (MWIN * 32)
__global__ __launch_bounds__(256) void k_pool_all(const float* __restrict__ kv_in,
                                                  _Float16* __restrict__ kv_out,
                                                  const float* __restrict__ s_in,
                                                  _Float16* __restrict__ s_out) {
    int idx = blockIdx.x * 256 + threadIdx.x;
    const float* in;
    _Float16* outp;
    int w, rest, shift;
    if (idx < KV4) {
        w = idx >> 9; rest = idx & 511; shift = 9;
        in = kv_in; outp = kv_out;
    } else {
        int j = idx - KV4;
        if (j >= S4) return;
        w = j >> 5; rest = j & 31; shift = 5;
        in = s_in; outp = s_out;
        idx = j;
    }
    int b = w >> 10, y = (w >> 5) & 31, xx = w & 31;
    f32x4 acc = {0.f, 0.f, 0.f, 0.f};
    #pragma unroll
    for (int dy = -1; dy <= 1; ++dy)
        #pragma unroll
        for (int dx = -1; dx <= 1; ++dx) {
            int ny = y + dy, nx = xx + dx;
            if (ny < 0 || ny >= 32 || nx < 0 || nx >= 32) continue;
            int nw = (b << 10) | (ny << 5) | nx;
            f32x4 v = ((const f32x4*)in)[((size_t)nw << shift) + rest];
            acc += v;
        }
    half4 hv;
    hv[0] = (_Float16)acc[0]; hv[1] = (_Float16)acc[1];
    hv[2] = (_Float16)acc[2]; hv[3] = (_Float16)acc[3];
    ((half4*)outp)[idx] = hv;
}

// ---------------- linear attention: one wave per window, MFMA-based ----------------
__global__ __launch_bounds__(256) void k_attn(const _Float16* __restrict__ qkv,
                                              const _Float16* __restrict__ kvp,
                                              const _Float16* __restrict__ sp,
                                              const int* __restrict__ offsets,
                                              const int* __restrict__ counts,
                                              _Float16* __restrict__ y_h) {
    int w = blockIdx.x * 4 + (threadIdx.x >> 6);
    int lane = threadIdx.x & 63;
    int col = lane & 15;
    int kq = lane >> 4;
    int off = offsets[w], cnt = counts[w];
    bool klive = kq < 2;
    int koff = (kq & 1) * 8;
    half8 zf = {};
    for (int h = 0; h < 8; ++h) {
        half8 t = *(const half8*)(kvp + ((((size_t)(w * HH + h)) << 8) + col * 16 + koff));
        half8 a_kv = klive ? t : zf;
        half8 t2 = *(const half8*)(sp + ((((size_t)(w * HH + h)) << 4) + koff));
        half8 a_s = klive ? t2 : zf;
        #pragma unroll
        for (int c = 0; c < 3; ++c) {
            int p = c * 16 + col;
            int pc = p < cnt ? p : cnt - 1;
            half8 qv = *(const half8*)(qkv + (size_t)(off + pc) * 384 + h * 16 + koff);
            #pragma unroll
            for (int i = 0; i < 8; ++i) qv[i] = qv[i] > (_Float16)0 ? qv[i] : (_Float16)0;
            half8 b_q = klive ? qv : zf;
            f32x4 acc = {};
            acc = __builtin_amdgcn_mfma_f32_16x16x32_f16(a_kv, b_q, acc, 0, 0, 0);
            f32x4 accs = {};
            accs = __builtin_amdgcn_mfma_f32_16x16x32_f16(a_s, b_q, accs, 0, 0, 0);
            float zinv = 1.f / (accs[0] + 1e-6f);
            half4 yo;
            #pragma unroll
            for (int i = 0; i < 4; ++i) yo[i] = (_Float16)(acc[i] * zinv);
            if (p < cnt)
                *(half4*)(y_h + (size_t)(off + p) * 128 + h * 16 + kq * 4) = yo;
        }
    }
}

extern "C" void kernel_launch(void* const* d_in, const int* in_sizes, int n_in,
                              void* d_out, int out_size, void* d_ws, size_t ws_size,
                              hipStream_t stream) {
    const float* x     = (const float*)d_in[0];
    const float* Wqkv  = (const float*)d_in[1];
    const float* Wproj = (const float*)d_in[2];
    const float* bproj = (const float*)d_in[3];
    const int*   offsets = (const int*)d_in[4];
    const int*   counts  = (const int*)d_in[5];

    int N = in_sizes[0] / 128;

    char* ws = (char*)d_ws;
    float* kv_t = (float*)ws;                                    ws += (size_t)MWIN * HH * 256 * 4;
    float* s    = (float*)ws;                                    ws += (size_t)MWIN * HH * 16 * 4;
    _Float16* kvpt = (_Float16*)ws;                              ws += (size_t)MWIN * HH * 256 * 2;
    _Float16* sp   = (_Float16*)ws;                              ws += (size_t)MWIN * HH * 16 * 2;
    _Float16* x_h    = (_Float16*)ws;                            ws += (size_t)N * 128 * 2;
    _Float16* qkv_h  = (_Float16*)ws;                            ws += (size_t)N * 384 * 2;
    _Float16* y_h    = (_Float16*)ws;                            ws += (size_t)N * 128 * 2;
    _Float16* Wqkv_h = (_Float16*)ws;                            ws += (size_t)384 * 128 * 2;
    _Float16* Wp_h   = (_Float16*)ws;                            ws += (size_t)128 * 128 * 2;
    float* out  = (float*)d_out;

    int n8x = N * 128 / 8;
    k_cvt<<<(n8x + 255) / 256, 256, 0, stream>>>(x, x_h, n8x);
    k_cvt<<<(384 * 128 / 8 + 255) / 256, 256, 0, stream>>>(Wqkv, Wqkv_h, 384 * 128 / 8);
    k_cvt<<<(128 * 128 / 8 + 255) / 256, 256, 0, stream>>>(Wproj, Wp_h, 128 * 128 / 8);

    k_mfma_gemm<_Float16><<<(N + 255) / 256, 256, 0, stream>>>(x_h, Wqkv_h, nullptr, qkv_h, 384, N, 6);

    k_kv_accum<<<MWIN, 256, 0, stream>>>(qkv_h, offsets, counts, kv_t, s);

    k_pool_all<<<(KV4 + S4 + 255) / 256, 256, 0, stream>>>(kv_t, kvpt, s, sp);

    k_attn<<<MWIN / 4, 256, 0, stream>>>(qkv_h, kvpt, sp, offsets, counts, y_h);

    k_mfma_gemm<float><<<(N + 255) / 256, 256, 0, stream>>>(y_h, Wp_h, bproj, out, 128, N, 2);
}